// Round 2
// baseline (356.940 us; speedup 1.0000x reference)
//
#include <hip/hip_runtime.h>
#include <hip/hip_bf16.h>

// PointerNet: out[b][k] = sum_c C_k[b,c] * sigmoid(WP[b,c]+WC_k[b,c]+Gb[c]) * (WPo[b,c]+Ob[c])
//   GEMM A: WPcat = P @ [GateWeight_P | OutWeight]  (M=8192,N=2048,K=1024), output INTERLEAVED:
//           uint32 WPcat[b][c] = (bf16 wp, bf16 wpo) so the epilogue gets both in one load.
//   GEMM B: WC_k = C_k @ GateWeight_C fused with sigmoid/dot epilogue (atomicAdd out).
// R7 (= R6 hardened after container-level failure):
//   - 256x256 tile / BK=32 / 8 waves / 4-deep LDS ring (4 x 32KB = 128KB), counted
//     s_waitcnt vmcnt(8) in the main loop (never drained, T4), one barrier per K-tile
//     (32 MFMA/wave between barriers).
//   - barrier is now __builtin_amdgcn_s_barrier() (compiler-visible convergence, same
//     as the verified 8-phase template) instead of raw asm.
//   - LDS swizzle seg^=(row>>1)&3: covers all 8 bank-groups across 8 rows -> residual
//     2-way conflict only (free per m136). R5's (row>>2) variant was 4-way (1.58x).
//   - T5: s_setprio(1)/(0) around the MFMA cluster.
//   - Epilogue: Gb/Ob hoisted per-ni, wp/wpo single-u32 loads from interleaved WPcat.

#define B_  8192
#define PD_ 1024
#define CD_ 1024

typedef unsigned short ushort_t;
typedef unsigned int   uint_t;
typedef __attribute__((ext_vector_type(8))) short    short8;
typedef __attribute__((ext_vector_type(4))) float    floatx4;

__device__ __forceinline__ float bf2f(unsigned short u) {
    return __uint_as_float(((unsigned)u) << 16);
}
__device__ __forceinline__ unsigned short f2bf(float f) {
    unsigned u = __float_as_uint(f);
    unsigned r = u + 0x7FFFu + ((u >> 16) & 1u);   // RNE
    return (unsigned short)(r >> 16);
}

// ---------------- prep: cast P,C1..C4 -> bf16; transpose 3 weights; zero out ----------------
__global__ __launch_bounds__(256) void prep_kernel(const float* __restrict__ P,
                                                   const float* __restrict__ C1,
                                                   const float* __restrict__ C2,
                                                   const float* __restrict__ C3,
                                                   const float* __restrict__ C4,
                                                   const float* __restrict__ GWP,
                                                   const float* __restrict__ OW,
                                                   const float* __restrict__ GWC,
                                                   ushort_t* __restrict__ Pb,
                                                   ushort_t* __restrict__ Call,
                                                   ushort_t* __restrict__ Wcat,
                                                   ushort_t* __restrict__ GWCt,
                                                   float* __restrict__ out) {
    const int bid = blockIdx.x;
    const int tid = threadIdx.x;
    if (bid < 40960) {
        const int seg = bid >> 13;
        const int i   = (bid & 8191) * 256 + tid;
        const float* src;
        ushort_t* dst;
        switch (seg) {
            case 0: src = P;  dst = Pb; break;
            case 1: src = C1; dst = Call; break;
            case 2: src = C2; dst = Call + (size_t)1 * B_ * CD_; break;
            case 3: src = C3; dst = Call + (size_t)2 * B_ * CD_; break;
            default: src = C4; dst = Call + (size_t)3 * B_ * CD_; break;
        }
        float4 v = ((const float4*)src)[i];
        ushort4 o;
        o.x = f2bf(v.x); o.y = f2bf(v.y); o.z = f2bf(v.z); o.w = f2bf(v.w);
        ((ushort4*)dst)[i] = o;
    } else if (bid < 44032) {
        __shared__ float tile[32][33];
        const int tb  = bid - 40960;
        const int seg = tb >> 10;
        const int t32 = tb & 1023;
        const float* src;
        ushort_t* dst;
        switch (seg) {
            case 0: src = GWP; dst = Wcat; break;
            case 1: src = OW;  dst = Wcat + 1024 * 1024; break;
            default: src = GWC; dst = GWCt; break;
        }
        const int c0 = (t32 & 31) * 32, r0 = (t32 >> 5) * 32;
        const int x = tid & 31, y = tid >> 5;
        for (int i = y; i < 32; i += 8)
            tile[i][x] = src[(size_t)(r0 + i) * 1024 + c0 + x];
        __syncthreads();
        for (int i = y; i < 32; i += 8)
            dst[(size_t)(c0 + i) * 1024 + r0 + x] = f2bf(tile[x][i]);
    } else {
        const int i = (bid - 44032) * 256 + tid;
        ((float4*)out)[i] = float4{0.f, 0.f, 0.f, 0.f};
    }
}

__device__ __forceinline__ void gl_lds16(const void* g, void* l) {
    __builtin_amdgcn_global_load_lds((const __attribute__((address_space(1))) void*)g,
                                     (__attribute__((address_space(3))) void*)l, 16, 0, 0);
}

#define VM8()  asm volatile("s_waitcnt vmcnt(8)" ::: "memory")
#define VM4()  asm volatile("s_waitcnt vmcnt(4)" ::: "memory")
#define VM0()  asm volatile("s_waitcnt vmcnt(0)" ::: "memory")
#define BARR() __builtin_amdgcn_s_barrier()

// ---------------- common 256x256 / BK=32 / 4-deep-ring pipelined K-loop ----------------
// LDS buffer kt&3: A tile 256x32 at base, B tile 256x32 at base+8192 (elems). Swizzle:
// 16B segment stored at seg_lds = seg_global ^ ((row>>1)&3)  (involution, both sides).
// Ledger (per-wave, 4 gl_lds per K-tile): iter t does {vmcnt(8); s_barrier; stage(t+3);
// ds_read(t); MFMA}. At the wait, stages t+1,t+2 (=8 loads) may remain in flight, so
// stage-t is retired (in-order VMEM retirement); the barrier publishes that across
// waves. stage(t+3) overwrites the buffer last READ at iter t-1; those ds_reads
// completed before each wave's t-1 MFMAs, hence before it crossed this barrier.
// Tail: vmcnt(8)/(8)/(4)/(0).
__device__ __forceinline__ void gemm256_pipeline(const ushort_t* __restrict__ A,
                                                 const ushort_t* __restrict__ Bt,
                                                 int tileM, int tileN,
                                                 ushort_t* smem,
                                                 floatx4 (&acc)[8][4]) {
    const int K = 1024;
    const int t = threadIdx.x;
    const int w = t >> 6, lane = t & 63;
    const int quad = lane >> 4, l16 = lane & 15;
    const int wm = w >> 2, wn = w & 3;

    // staging: wave w, load i in {0,1} covers rows w*16 + (lane>>2) + i*128 of each tile;
    // global 16B-segment pre-swizzled so LDS dest stays linear (rule #21).
    const int segg = ((lane & 3) ^ ((lane >> 3) & 3)) * 8;
    const ushort_t* Ap0 = A  + (size_t)(tileM + w * 16 + (lane >> 2)) * K + segg;
    const ushort_t* Ap1 = Ap0 + (size_t)128 * K;
    const ushort_t* Bp0 = Bt + (size_t)(tileN + w * 16 + (lane >> 2)) * K + segg;
    const ushort_t* Bp1 = Bp0 + (size_t)128 * K;
    const int lA0 = w * 512 + lane * 8;        // elem offsets within a ring buffer
    const int lA1 = lA0 + 4096;
    const int lB0 = 8192 + lA0;
    const int lB1 = lB0 + 4096;

    // fragment reads: row = (wm*128|wn*64) + {mi,ni}*16 + l16, k-seg quad, swizzled.
    const int xs  = (quad ^ ((l16 >> 1) & 3)) * 8;
    const int roA = (wm * 128 + l16) * 32 + xs;
    const int roB = 8192 + (wn * 64 + l16) * 32 + xs;

#pragma unroll
    for (int i = 0; i < 8; i++)
#pragma unroll
        for (int j = 0; j < 4; j++) acc[i][j] = (floatx4)0.f;

#define STAGE(kt) do {                                                       \
        const int base_ = ((kt) & 3) * 16384; const int k0_ = (kt) * 32;     \
        gl_lds16(Ap0 + k0_, &smem[base_ + lA0]);                             \
        gl_lds16(Ap1 + k0_, &smem[base_ + lA1]);                             \
        gl_lds16(Bp0 + k0_, &smem[base_ + lB0]);                             \
        gl_lds16(Bp1 + k0_, &smem[base_ + lB1]); } while (0)

#define COMPUTE(kt) do {                                                     \
        const int base_ = ((kt) & 3) * 16384;                                \
        short8 af_[8], bf_[4];                                               \
        _Pragma("unroll")                                                    \
        for (int mi = 0; mi < 8; mi++)                                       \
            af_[mi] = *(const short8*)&smem[base_ + roA + mi * 512];         \
        _Pragma("unroll")                                                    \
        for (int ni = 0; ni < 4; ni++)                                       \
            bf_[ni] = *(const short8*)&smem[base_ + roB + ni * 512];         \
        __builtin_amdgcn_s_setprio(1);                                       \
        _Pragma("unroll")                                                    \
        for (int mi = 0; mi < 8; mi++)                                       \
        _Pragma("unroll")                                                    \
        for (int ni = 0; ni < 4; ni++)                                       \
            acc[mi][ni] = __builtin_amdgcn_mfma_f32_16x16x32_bf16(           \
                af_[mi], bf_[ni], acc[mi][ni], 0, 0, 0);                     \
        __builtin_amdgcn_s_setprio(0); } while (0)

    STAGE(0); STAGE(1); STAGE(2);
#pragma unroll 4
    for (int kt = 0; kt < 28; ++kt) {
        VM8(); BARR();
        STAGE(kt + 3);
        COMPUTE(kt);
    }
    VM8(); BARR(); STAGE(31); COMPUTE(28);
    VM8(); BARR(); COMPUTE(29);
    VM4(); BARR(); COMPUTE(30);
    VM0(); BARR(); COMPUTE(31);
#undef STAGE
#undef COMPUTE
}

// ---------------- GEMM A: WPcat(interleaved) = Pb @ Wcat^T  (256x256 tile, 512 thr) ----------------
// grid 256: xcd=bid&7, q=bid>>3; slab=(q>>3)*8+xcd (32 slabs), colt=q&7 (8 col tiles).
__global__ __launch_bounds__(512, 2) void gemmA_k(const ushort_t* __restrict__ A,
                                                  const ushort_t* __restrict__ Bt,
                                                  ushort_t* __restrict__ C) {
    __shared__ ushort_t smem[65536];     // 128 KB: 4 ring buffers x (A 8192 + B 8192 elems)
    const int xcd = blockIdx.x & 7, q = blockIdx.x >> 3;
    const int tileM = ((q >> 3) * 8 + xcd) * 256;
    const int tileN = (q & 7) * 256;

    floatx4 acc[8][4];
    gemm256_pipeline(A, Bt, tileM, tileN, smem, acc);

    const int t = threadIdx.x, lane = t & 63, quad = lane >> 4, l16 = lane & 15;
    const int w = t >> 6, wm = w >> 2, wn = w & 3;
    const int rowb = tileM + wm * 128 + quad * 4;
#pragma unroll
    for (int mi = 0; mi < 8; mi++)
#pragma unroll
        for (int ni = 0; ni < 4; ni++) {
            const int col = tileN + wn * 64 + ni * 16 + l16;
            const int ci = col & 1023, hi = col >> 10;    // interleave: (wp,wpo) per uint32
#pragma unroll
            for (int r = 0; r < 4; r++) {
                const int row = rowb + mi * 16 + r;
                C[(size_t)(row * 1024 + ci) * 2 + hi] = f2bf(acc[mi][ni][r]);
            }
        }
}

// ---------------- GEMM B + register-direct fused epilogue (256x256 tile, 512 thr) ----------------
// grid 512: xcd=bid&7, q=bid>>3; slab=(q>>2)*8+xcd (128 slabs), colt=q&3 (4 col tiles).
__global__ __launch_bounds__(512, 2) void gemmB_fused(const ushort_t* __restrict__ Call,
                                                      const ushort_t* __restrict__ GWCt,
                                                      const uint_t* __restrict__ WPcat,
                                                      const float* __restrict__ Gb,
                                                      const float* __restrict__ Ob,
                                                      float* __restrict__ out) {
    __shared__ ushort_t smem[65536];     // 128 KB ring
    const int xcd = blockIdx.x & 7, q = blockIdx.x >> 3;
    const int tileM = ((q >> 2) * 8 + xcd) * 256;
    const int tileN = (q & 3) * 256;

    floatx4 acc[8][4];
    gemm256_pipeline(Call, GWCt, tileM, tileN, smem, acc);

    const int t = threadIdx.x, lane = t & 63, quad = lane >> 4, l16 = lane & 15;
    const int w = t >> 6, wm = w >> 2, wn = w & 3;

    const int kk    = tileM >> 13;                         // choice index (uniform per block)
    const int b0    = (tileM & 8191) + wm * 128 + quad * 4;  // batch row base (+mi*16+r)
    const int rowg0 = tileM + wm * 128 + quad * 4;           // Call row base (+mi*16+r)

    float gbv[4], obv[4];
    int   gcol[4];
#pragma unroll
    for (int ni = 0; ni < 4; ni++) {
        gcol[ni] = tileN + wn * 64 + ni * 16 + l16;
        gbv[ni]  = Gb[gcol[ni]];
        obv[ni]  = Ob[gcol[ni]];
    }

#pragma unroll
    for (int mi = 0; mi < 8; mi++) {
        float part[4] = {0.f, 0.f, 0.f, 0.f};
#pragma unroll
        for (int ni = 0; ni < 4; ni++) {
            const uint_t*   wpp = WPcat + (size_t)(b0 + mi * 16) * 1024 + gcol[ni];
            const ushort_t* ckp = Call  + (size_t)(rowg0 + mi * 16) * 1024 + gcol[ni];
#pragma unroll
            for (int r = 0; r < 4; r++) {
                const uint_t wpair = wpp[(size_t)r * 1024];
                const float wp  = bf2f((unsigned short)(wpair & 0xffffu));
                const float wpo = bf2f((unsigned short)(wpair >> 16));
                const float ck  = bf2f(ckp[(size_t)r * 1024]);
                const float x = wp + acc[mi][ni][r] + gbv[ni];   // WC stays fp32
                const float g = 1.f / (1.f + __expf(-x));
                part[r] += ck * g * (wpo + obv[ni]);
            }
        }
#pragma unroll
        for (int r = 0; r < 4; r++) {                    // reduce across 16-lane quad group
            part[r] += __shfl_xor(part[r], 1);
            part[r] += __shfl_xor(part[r], 2);
            part[r] += __shfl_xor(part[r], 4);
            part[r] += __shfl_xor(part[r], 8);
        }
        if (l16 == 0) {
#pragma unroll
            for (int r = 0; r < 4; r++)
                atomicAdd(&out[(size_t)(b0 + mi * 16 + r) * 4 + kk], part[r]);
        }
    }
}

extern "C" void kernel_launch(void* const* d_in, const int* in_sizes, int n_in,
                              void* d_out, int out_size, void* d_ws, size_t ws_size,
                              hipStream_t stream) {
    (void)in_sizes; (void)n_in; (void)out_size; (void)ws_size;
    const float* P   = (const float*)d_in[0];
    const float* C1  = (const float*)d_in[1];
    const float* C2  = (const float*)d_in[2];
    const float* C3  = (const float*)d_in[3];
    const float* C4  = (const float*)d_in[4];
    const float* GWP = (const float*)d_in[5];
    const float* GWC = (const float*)d_in[6];
    const float* Gb  = (const float*)d_in[7];
    const float* OW  = (const float*)d_in[8];
    const float* Ob  = (const float*)d_in[9];
    float* out = (float*)d_out;

    // workspace (bf16): Pb 16MiB | Call 64MiB | Wcat 4MiB | GWCt 2MiB | WPcat 32MiB
    char* ws = (char*)d_ws;
    ushort_t* Pb    = (ushort_t*)(ws);
    ushort_t* Call  = (ushort_t*)(ws + (16u << 20));
    ushort_t* Wcat  = (ushort_t*)(ws + (80u << 20));
    ushort_t* GWCt  = (ushort_t*)(ws + (84u << 20));
    ushort_t* WPcat = (ushort_t*)(ws + (86u << 20));

    prep_kernel<<<44064, 256, 0, stream>>>(P, C1, C2, C3, C4, GWP, OW, GWC,
                                           Pb, Call, Wcat, GWCt, out);
    gemmA_k<<<256, 512, 0, stream>>>(Pb, Wcat, WPcat);
    gemmB_fused<<<512, 512, 0, stream>>>(Call, GWCt, (const uint_t*)WPcat, Gb, Ob, out);
}